// Round 1
// baseline (4281.971 us; speedup 1.0000x reference)
//
#include <hip/hip_runtime.h>
#include <hip/hip_bf16.h>

typedef __attribute__((ext_vector_type(8))) short short8;
typedef __attribute__((ext_vector_type(4))) float floatx4;
typedef unsigned short u16;

// B=128, T=256, D=6, H=512, 4H=2048, NC=4, PS=12

__device__ __forceinline__ u16 f2b(float f){
  union { float fl; unsigned u; } v; v.fl = f;
  unsigned r = v.u + 0x7fffu + ((v.u >> 16) & 1u);   // RNE bf16
  return (u16)(r >> 16);
}

struct StepP {
  const u16* A1; const u16* W1;   // phase-1 operand (input proj), row-major K1-contig
  const u16* A2; const u16* W2;   // phase-2 operand (recurrent), K=512
  const float* bias;              // 2048 fp32, gate-interleaved (r' = 4j+gate)
  float* c;                       // fp32 cell state [128][512]
  u16* hb;                        // bf16 h out [128][512]
  float* hf;                      // optional fp32 h out
  int K1; int active;
};

// ---------------- prep kernels ----------------

// (2048,512) fp32 -> bf16, rows reordered r=gate*512+j -> r'=j*4+gate
__global__ void reorder_w_k(const float* __restrict__ W, u16* __restrict__ out){
  int idx = blockIdx.x*256 + threadIdx.x;       // 2048*512
  int r = idx >> 9, k = idx & 511;
  int rp = ((r & 511) << 2) | (r >> 9);
  out[rp*512 + k] = f2b(W[idx]);
}

// enc_Wih0 (2048,6) -> (2048,32) bf16 zero-padded, rows reordered
__global__ void prep_wx0_k(const float* __restrict__ W, u16* __restrict__ out){
  int idx = blockIdx.x*256 + threadIdx.x;       // 2048*32
  int r = idx >> 5, k = idx & 31;
  int rp = ((r & 511) << 2) | (r >> 9);
  out[rp*32 + k] = (k < 6) ? f2b(W[r*6 + k]) : (u16)0;
}

__global__ void prep_bias_k(const float* __restrict__ bih, const float* __restrict__ bhh,
                            float* __restrict__ out){
  int r = blockIdx.x*256 + threadIdx.x;         // 2048
  int rp = ((r & 511) << 2) | (r >> 9);
  out[rp] = bih[r] + bhh[r];
}

// x (B,T,6) fp32 -> Xb (T,B,32) bf16 zero-padded
__global__ void prep_x_k(const float* __restrict__ x, u16* __restrict__ out){
  int idx = blockIdx.x*256 + threadIdx.x;       // 256*128*32
  int t = idx >> 12; int rem = idx & 4095; int b = rem >> 5; int k = rem & 31;
  out[idx] = (k < 6) ? f2b(x[(b*256 + t)*6 + k]) : (u16)0;
}

// ---------------- LSTM step (GEMM + fused cell update) ----------------
// gates[b][r'] = bias[r'] + sum_k A1[b][k] W1[r'][k] + sum_k A2[b][k] W2[r'][k]
// WG grid 256: mt = wg&7 (16 batch rows), nt = wg>>3 (64 gate cols = 16 j, all 4 gates)

__device__ __forceinline__ void lstm_step_body(StepP p, int wg){
  const int tid  = threadIdx.x;
  const int wave = tid >> 6;
  const int lane = tid & 63;
  const int lrow = lane & 15;     // A-row (m) / B-row (n) within 16
  const int kq   = lane >> 4;     // k chunk: k = kq*8 + j
  const int mt = wg & 7;
  const int nt = wg >> 3;
  const int m  = mt*16 + lrow;
  const int nb = nt*64 + wave*16 + lrow;   // global gate column r'
  floatx4 acc = {0.f, 0.f, 0.f, 0.f};
  {
    const u16* Ap = p.A1 + m*p.K1 + kq*8;
    const u16* Wp = p.W1 + nb*p.K1 + kq*8;
    for (int kc = 0; kc < p.K1; kc += 32){
      short8 a = *(const short8*)(Ap + kc);
      short8 b = *(const short8*)(Wp + kc);
      acc = __builtin_amdgcn_mfma_f32_16x16x32_bf16(a, b, acc, 0, 0, 0);
    }
  }
  {
    const u16* Ap = p.A2 + m*512 + kq*8;
    const u16* Wp = p.W2 + nb*512 + kq*8;
    #pragma unroll 4
    for (int kc = 0; kc < 512; kc += 32){
      short8 a = *(const short8*)(Ap + kc);
      short8 b = *(const short8*)(Wp + kc);
      acc = __builtin_amdgcn_mfma_f32_16x16x32_bf16(a, b, acc, 0, 0, 0);
    }
  }
  // C/D layout (verified): row(m) = (lane>>4)*4 + reg, col(n) = lane&15
  __shared__ float g[16][65];
  const float bn = p.bias[nb];
  const int col = wave*16 + lrow;
  #pragma unroll
  for (int r = 0; r < 4; ++r) g[kq*4 + r][col] = acc[r] + bn;
  __syncthreads();
  // cell update: one thread per (batch-local, j-local)
  const int bl = tid & 15;
  const int jl = tid >> 4;
  float gi = g[bl][jl*4+0];
  float gf = g[bl][jl*4+1];
  float gg = g[bl][jl*4+2];
  float go = g[bl][jl*4+3];
  const int idx = (mt*16 + bl)*512 + nt*16 + jl;
  float cold = p.c[idx];
  float iv = 1.f/(1.f + expf(-gi));
  float fv = 1.f/(1.f + expf(-gf));
  float ov = 1.f/(1.f + expf(-go));
  float gv = tanhf(gg);
  float cn = fv*cold + iv*gv;
  float hn = ov * tanhf(cn);
  p.c[idx]  = cn;
  p.hb[idx] = f2b(hn);
  if (p.hf) p.hf[idx] = hn;
}

__global__ __launch_bounds__(256) void lstm_step2_k(StepP p0, StepP p1){
  if (blockIdx.x < 256){ if (p0.active) lstm_step_body(p0, blockIdx.x); }
  else                 { if (p1.active) lstm_step_body(p1, blockIdx.x - 256); }
}

__global__ __launch_bounds__(256) void lstm_step1_k(StepP p){
  lstm_step_body(p, blockIdx.x);
}

// ---------------- heads ----------------

__global__ void heads_k(const float* __restrict__ h1f,
                        const float* __restrict__ clsW, const float* __restrict__ clsb,
                        const float* __restrict__ regW, const float* __restrict__ regb,
                        float* __restrict__ out){
  int b = blockIdx.x; int lane = threadIdx.x;   // block 64
  float a[5] = {0,0,0,0,0};
  for (int kk = 0; kk < 8; ++kk){
    float hv = h1f[b*512 + kk*64 + lane];
    #pragma unroll
    for (int d = 0; d < 4; ++d) a[d] += hv * clsW[d*512 + kk*64 + lane];
    a[4] += hv * regW[kk*64 + lane];
  }
  #pragma unroll
  for (int d = 0; d < 5; ++d){
    float v = a[d];
    for (int off = 32; off; off >>= 1) v += __shfl_down(v, off);
    if (lane == 0){
      if (d < 4) out[9216 + b*4 + d] = v + clsb[d];
      else       out[9728 + b]       = v + regb[0];
    }
  }
}

__global__ void pred_k(const float* __restrict__ h1f,
                       const float* __restrict__ fcW, const float* __restrict__ fcb,
                       float* __restrict__ out, int s){
  int b = blockIdx.x; int lane = threadIdx.x;   // block 64
  float a[6] = {0,0,0,0,0,0};
  for (int kk = 0; kk < 8; ++kk){
    float hv = h1f[b*512 + kk*64 + lane];
    #pragma unroll
    for (int d = 0; d < 6; ++d) a[d] += hv * fcW[d*512 + kk*64 + lane];
  }
  #pragma unroll
  for (int d = 0; d < 6; ++d){
    float v = a[d];
    for (int off = 32; off; off >>= 1) v += __shfl_down(v, off);
    if (lane == 0) out[b*72 + s*6 + d] = v + fcb[d];
  }
}

// ---------------- launcher ----------------

extern "C" void kernel_launch(void* const* d_in, const int* in_sizes, int n_in,
                              void* d_out, int out_size, void* d_ws, size_t ws_size,
                              hipStream_t stream){
  const float* x        = (const float*)d_in[0];
  const float* eWih0    = (const float*)d_in[1];
  const float* eWhh0    = (const float*)d_in[2];
  const float* ebih0    = (const float*)d_in[3];
  const float* ebhh0    = (const float*)d_in[4];
  const float* eWih1    = (const float*)d_in[5];
  const float* eWhh1    = (const float*)d_in[6];
  const float* ebih1    = (const float*)d_in[7];
  const float* ebhh1    = (const float*)d_in[8];
  const float* dWih0    = (const float*)d_in[9];
  const float* dWhh0    = (const float*)d_in[10];
  const float* dbih0    = (const float*)d_in[11];
  const float* dbhh0    = (const float*)d_in[12];
  const float* dWih1    = (const float*)d_in[13];
  const float* dWhh1    = (const float*)d_in[14];
  const float* dbih1    = (const float*)d_in[15];
  const float* dbhh1    = (const float*)d_in[16];
  const float* fcW      = (const float*)d_in[17];
  const float* fcb      = (const float*)d_in[18];
  const float* clsW     = (const float*)d_in[19];
  const float* clsb     = (const float*)d_in[20];
  const float* regW     = (const float*)d_in[21];
  const float* regb     = (const float*)d_in[22];
  float* out = (float*)d_out;

  uintptr_t base = (uintptr_t)d_ws;
  auto carve = [&](size_t n)->void*{
    void* p = (void*)base; base += (n + 255) & ~(size_t)255; return p;
  };
  u16* Wx0b  = (u16*)carve(2048*32*2);
  u16* We0hh = (u16*)carve(2048*512*2);
  u16* We1ih = (u16*)carve(2048*512*2);
  u16* We1hh = (u16*)carve(2048*512*2);
  u16* Wd0ih = (u16*)carve(2048*512*2);
  u16* Wd0hh = (u16*)carve(2048*512*2);
  u16* Wd1ih = (u16*)carve(2048*512*2);
  u16* Wd1hh = (u16*)carve(2048*512*2);
  float* Bs  = (float*)carve(4*2048*4);          // enc0, enc1, dec0, dec1
  u16* Xb    = (u16*)carve(256*128*32*2);
  u16* h0b   = (u16*)carve(2*128*512*2);         // ping-pong
  u16* h1b   = (u16*)carve(2*128*512*2);
  float* c0  = (float*)carve(128*512*4);
  float* c1  = (float*)carve(128*512*4);
  float* h1f = (float*)carve(128*512*4);

  // zero states: h0b, h1b, c0, c1 are contiguous (all 256-aligned sizes)
  hipMemsetAsync(h0b, 0, 2*128*512*2 + 2*128*512*2 + 128*512*4 + 128*512*4, stream);

  reorder_w_k<<<4096,256,0,stream>>>(eWhh0, We0hh);
  reorder_w_k<<<4096,256,0,stream>>>(eWih1, We1ih);
  reorder_w_k<<<4096,256,0,stream>>>(eWhh1, We1hh);
  reorder_w_k<<<4096,256,0,stream>>>(dWih0, Wd0ih);
  reorder_w_k<<<4096,256,0,stream>>>(dWhh0, Wd0hh);
  reorder_w_k<<<4096,256,0,stream>>>(dWih1, Wd1ih);
  reorder_w_k<<<4096,256,0,stream>>>(dWhh1, Wd1hh);
  prep_wx0_k<<<256,256,0,stream>>>(eWih0, Wx0b);
  prep_bias_k<<<8,256,0,stream>>>(ebih0, ebhh0, Bs);
  prep_bias_k<<<8,256,0,stream>>>(ebih1, ebhh1, Bs + 2048);
  prep_bias_k<<<8,256,0,stream>>>(dbih0, dbhh0, Bs + 4096);
  prep_bias_k<<<8,256,0,stream>>>(dbih1, dbhh1, Bs + 6144);
  prep_x_k<<<4096,256,0,stream>>>(x, Xb);

  const int HB = 128*512;   // elements per h buffer
  // encoder: pipelined — launch l runs layer0 step t=l and layer1 step u=l-1
  for (int l = 0; l <= 256; ++l){
    StepP p0 = {}; StepP p1 = {};
    if (l < 256){
      int t = l;
      p0.A1 = Xb + t*4096;            p0.W1 = Wx0b;  p0.K1 = 32;
      p0.A2 = h0b + ((t+1)&1)*HB;     p0.W2 = We0hh;
      p0.bias = Bs;                   p0.c = c0;
      p0.hb = h0b + (t&1)*HB;         p0.hf = nullptr;
      p0.active = 1;
    }
    if (l >= 1){
      int u = l - 1;
      p1.A1 = h0b + (u&1)*HB;         p1.W1 = We1ih; p1.K1 = 512;
      p1.A2 = h1b + ((u+1)&1)*HB;     p1.W2 = We1hh;
      p1.bias = Bs + 2048;            p1.c = c1;
      p1.hb = h1b + (u&1)*HB;         p1.hf = h1f;
      p1.active = 1;
    }
    lstm_step2_k<<<512,256,0,stream>>>(p0, p1);
  }

  // heads from last = h1 at t=255 (fp32 master) — before decoder overwrites h1f
  heads_k<<<128,64,0,stream>>>(h1f, clsW, clsb, regW, regb, out);

  // decoder: 12 sequential steps; encoder left h0b/h1b in buffer 1
  for (int s = 0; s < 12; ++s){
    int ps = (s & 1) ^ 1;
    StepP pc0 = {};
    pc0.A1 = h1b + ps*HB;        pc0.W1 = Wd0ih; pc0.K1 = 512;   // inp = prev h1
    pc0.A2 = h0b + ps*HB;        pc0.W2 = Wd0hh;
    pc0.bias = Bs + 4096;        pc0.c = c0;
    pc0.hb = h0b + (1-ps)*HB;    pc0.hf = nullptr;
    pc0.active = 1;
    lstm_step1_k<<<256,256,0,stream>>>(pc0);
    StepP pc1 = {};
    pc1.A1 = h0b + (1-ps)*HB;    pc1.W1 = Wd1ih; pc1.K1 = 512;   // inp = h0n
    pc1.A2 = h1b + ps*HB;        pc1.W2 = Wd1hh;
    pc1.bias = Bs + 6144;        pc1.c = c1;
    pc1.hb = h1b + (1-ps)*HB;    pc1.hf = h1f;
    pc1.active = 1;
    lstm_step1_k<<<256,256,0,stream>>>(pc1);
    pred_k<<<128,64,0,stream>>>(h1f, fcW, fcb, out, s);
  }
  (void)in_sizes; (void)n_in; (void)out_size; (void)ws_size;
}